// Round 4
// baseline (386.106 us; speedup 1.0000x reference)
//
#include <hip/hip_runtime.h>
#include <stdint.h>

#define MDIM 4096
#define KDIM 4096
#define NDIM 11008
#define KP   (KDIM/8)   // 512 packed int32 per N-row
#define NKT  (KDIM/64)  // 64 K-steps of BK=64

typedef float  f32x4  __attribute__((ext_vector_type(4)));
typedef __bf16 bf16x8 __attribute__((ext_vector_type(8)));
typedef unsigned short u16x8 __attribute__((ext_vector_type(8)));

// RNE f32 -> bf16 bits (matches jax astype(bf16) for non-NaN inputs)
__device__ __forceinline__ unsigned short f2bf(float f) {
  uint32_t u = __builtin_bit_cast(uint32_t, f);
  u += 0x7FFFu + ((u >> 16) & 1u);
  return (unsigned short)(u >> 16);
}
__device__ __forceinline__ float bf2f(unsigned short h) {
  return __builtin_bit_cast(float, (uint32_t)h << 16);
}
__device__ __forceinline__ float bf16r(float f) { return bf2f(f2bf(f)); }

// async global -> LDS, 16B per lane, wave-uniform LDS base + lane*16
__device__ __forceinline__ void lds16(const void* g, void* l) {
  __builtin_amdgcn_global_load_lds(
      (const __attribute__((address_space(1))) unsigned int*)g,
      (__attribute__((address_space(3))) unsigned int*)l, 16, 0, 0);
}

// ---------------- pre-pass 1: dequant packed int4 -> bf16 W[N][K] -----------
__global__ __launch_bounds__(256) void dequant_w_kernel(
    const uint32_t* __restrict__ wq, const float* __restrict__ scales,
    const float* __restrict__ zeros, u16x8* __restrict__ Wbf) {
  int idx = blockIdx.x * 256 + threadIdx.x;      // [0, N*KP)
  int n = idx >> 9;                              // idx / 512
  float s = bf16r(scales[n]);
  float z = bf16r(zeros[n]);
  uint32_t w = wq[idx];
  u16x8 v;
#pragma unroll
  for (int j = 0; j < 8; ++j) {
    float qf = (float)((w >> (4 * j)) & 0xF);
    float t  = bf16r(qf * s);                    // bf16 mul rounding
    v[j] = f2bf(t + z);                          // bf16 add rounding
  }
  Wbf[idx] = v;
}

// ---------------- pre-pass 2: x f32 -> bf16 ---------------------------------
__global__ __launch_bounds__(256) void convert_x_kernel(
    const float4* __restrict__ x, u16x8* __restrict__ Xbf) {
  int idx = blockIdx.x * 256 + threadIdx.x;
  float4 a = x[2 * idx], b = x[2 * idx + 1];
  u16x8 v;
  v[0] = f2bf(a.x); v[1] = f2bf(a.y); v[2] = f2bf(a.z); v[3] = f2bf(a.w);
  v[4] = f2bf(b.x); v[5] = f2bf(b.y); v[6] = f2bf(b.z); v[7] = f2bf(b.w);
  Xbf[idx] = v;
}

// ---------------- main GEMM: 256x256, BK=64, 8 waves, 4-phase/K-tile --------
// Round-3 structure + REGISTER-FRAGMENT PREFETCH: phase p's MFMAs consume
// fragments whose ds_reads were issued inside phase p-1's MFMA segment
// (one phase earlier), so lgkm waits vanish and the LDS pipe runs under the
// MFMA pipe instead of anti-correlated with it. A-frags ping-pong per phase
// (Af0/Af1), B-frags per ks-half (Bf0/Bf1) — LDS bytes unchanged.
// All prefetches of freshly-staged slots are issued only after the VMWAIT
// retiring that slot's global_load_lds AND the following barrier.
__global__ __launch_bounds__(512, 2) void gemm256_kernel(
    const unsigned short* __restrict__ Abf,
    const unsigned short* __restrict__ Bbf,
    const float* __restrict__ bias, float* __restrict__ out) {
  __shared__ __align__(16) char smem[131072];

  const int tid  = threadIdx.x;
  const int lane = tid & 63;
  const int wave = tid >> 6;     // 0..7
  const int wm   = wave >> 2;    // 0..1 : M half (128 rows)
  const int wn   = wave & 3;     // 0..3 : N quarter (64 cols)

  // XCD-aware bijective swizzle: 688 = 8 * 86 blocks.
  const int b   = blockIdx.x;
  const int swz = (b & 7) * 86 + (b >> 3);
  const int mt  = swz / 43;
  const int nt  = swz - mt * 43;
  const int bm0 = mt * 256, bn0 = nt * 256;

  // staging: inverse st_16x32 permutation on the SOURCE (round-1 verified)
  const int lp   = (lane >= 32) ? (lane ^ 2) : lane;
  const int srow = lp >> 2;        // 0..15
  const int scol = (lp & 3) << 3;  // 0,8,16,24 (bf16 elems)
  const unsigned short* aR = Abf + (size_t)(bm0 + wave * 32 + srow) * KDIM + scol;
  const unsigned short* bR = Bbf + (size_t)(bn0 + wave * 32 + srow) * KDIM + scol;

  // swizzled per-lane fragment-read offset within a 1KB subtile
  int rd = ((lane & 15) << 6) | ((lane >> 4) << 4);
  rd ^= ((lane >> 3) & 1) << 5;

  const int aoffc = wm * 8192;          // wm*8 subtiles
  const int boffc = 65536 + wn * 4096;  // B ring + wn*4 subtiles

  f32x4 acc[8][4];
#pragma unroll
  for (int i = 0; i < 8; ++i)
#pragma unroll
    for (int j = 0; j < 4; ++j) acc[i][j] = (f32x4){0.f, 0.f, 0.f, 0.f};

  bf16x8 Af[2][4], Bf[2][4];  // all indices compile-time constant (rule #20)

#define STAGE_HALF(srcR, ringoff, tile, ks, slot)                           \
  do {                                                                      \
    const unsigned short* s_ = (srcR) + (size_t)((tile) * 64 + (ks) * 32);  \
    char* d_ = smem + (ringoff) + ((slot) << 14) + wave * 2048;             \
    lds16(s_, d_);                                                          \
    lds16(s_ + (size_t)16 * KDIM, d_ + 1024);                               \
  } while (0)

#define READ_A(SET, slotbase, mfbase)                                       \
  _Pragma("unroll") for (int mf = 0; mf < 4; ++mf)                          \
      Af[SET][mf] = *(const bf16x8*)(smem + aoffc + (slotbase) +            \
                                     ((mfbase) + mf) * 1024 + rd);

#define READ_B(SET, slotbase)                                               \
  _Pragma("unroll") for (int nf = 0; nf < 4; ++nf)                          \
      Bf[SET][nf] = *(const bf16x8*)(smem + boffc + (slotbase) + nf * 1024 + rd);

#define MFMA16(ASET, BSET, mrow)                                            \
  __builtin_amdgcn_s_setprio(1);                                            \
  _Pragma("unroll") for (int mf = 0; mf < 4; ++mf)                          \
      _Pragma("unroll") for (int nf = 0; nf < 4; ++nf)                      \
          acc[(mrow) + mf][nf] = __builtin_amdgcn_mfma_f32_16x16x32_bf16(   \
              Af[ASET][mf], Bf[BSET][nf], acc[(mrow) + mf][nf], 0, 0, 0);   \
  __builtin_amdgcn_s_setprio(0);

#define BAR                                                                 \
  __builtin_amdgcn_s_barrier();                                             \
  __builtin_amdgcn_sched_barrier(0);

#define SB0 __builtin_amdgcn_sched_barrier(0);

#define VMWAIT(N) asm volatile("s_waitcnt vmcnt(" #N ")" ::: "memory")

  // TILE with fragment prefetch. S0s/S1s: slots of (T,ks0)/(T,ks1);
  // SN1s: slot for (T+1,ks1) staging; S0n: slot holding (T+1,ks0) (prefetch
  // source at p3). (T+2,ks0) is staged back into S0s. PF=0 on the last tile.
#define TILE(T, S0s, S1s, SN1s, S0n, NSTG, VM1STMT, VM3STMT, PF)            \
  do {                                                                      \
    /* p0: MFMA(ks0, mf0-3) = Af0,Bf0; prefetch Af1 <- (T,ks0,mf4-7) */     \
    if ((NSTG) >= 1) STAGE_HALF(aR, 0, (T) + 1, 1, SN1s);                   \
    BAR;                                                                    \
    READ_A(1, (S0s) << 14, 4);                                              \
    SB0;                                                                    \
    MFMA16(0, 0, 0);                                                        \
    BAR;                                                                    \
    /* p1: MFMA(ks0, mf4-7) = Af1,Bf0; prefetch Af0,Bf1 <- (T,ks1) */       \
    if ((NSTG) >= 2) STAGE_HALF(bR, 65536, (T) + 1, 1, SN1s);               \
    VM1STMT;                                                                \
    BAR;                                                                    \
    READ_A(0, (S1s) << 14, 0);                                              \
    READ_B(1, (S1s) << 14);                                                 \
    SB0;                                                                    \
    MFMA16(1, 0, 4);                                                        \
    BAR;                                                                    \
    /* p2: MFMA(ks1, mf0-3) = Af0,Bf1; prefetch Af1 <- (T,ks1,mf4-7) */     \
    if ((NSTG) >= 3) STAGE_HALF(aR, 0, (T) + 2, 0, S0s);                    \
    BAR;                                                                    \
    READ_A(1, (S1s) << 14, 4);                                              \
    SB0;                                                                    \
    MFMA16(0, 1, 0);                                                        \
    BAR;                                                                    \
    /* p3: MFMA(ks1, mf4-7) = Af1,Bf1; prefetch Af0,Bf0 <- (T+1,ks0) */     \
    if ((NSTG) >= 4) STAGE_HALF(bR, 65536, (T) + 2, 0, S0s);                \
    VM3STMT;                                                                \
    BAR;                                                                    \
    if (PF) { READ_A(0, (S0n) << 14, 0); READ_B(0, (S0n) << 14); }          \
    SB0;                                                                    \
    MFMA16(1, 1, 4);                                                        \
    BAR;                                                                    \
  } while (0)

  // prologue: A0(0),B0(0),A1(0),B1(0),A0(1),B0(1) = 12 loads; wait first 4
  STAGE_HALF(aR, 0, 0, 0, 0);
  STAGE_HALF(bR, 65536, 0, 0, 0);
  STAGE_HALF(aR, 0, 0, 1, 1);
  STAGE_HALF(bR, 65536, 0, 1, 1);
  STAGE_HALF(aR, 0, 1, 0, 2);
  STAGE_HALF(bR, 65536, 1, 0, 2);
  VMWAIT(8);
  BAR;
  // prime fragment set 0 with (0,ks0)
  READ_A(0, 0, 0);
  READ_B(0, 0);

  for (int tt = 0; tt < 62; tt += 2) {
    TILE(tt,     0, 1, 3, 2, 4, VMWAIT(8), VMWAIT(8), 1);
    TILE(tt + 1, 2, 3, 1, 0, 4, VMWAIT(8), VMWAIT(8), 1);
  }
  // t=62: stage only A1(63),B1(63); t=63: no staging, drain at p1
  TILE(62, 0, 1, 3, 2, 2, VMWAIT(8), VMWAIT(4), 1);
  TILE(63, 2, 3, 1, 0, 0, VMWAIT(0), (void)0, 0);

#undef TILE
#undef VMWAIT
#undef SB0
#undef BAR
#undef MFMA16
#undef READ_B
#undef READ_A
#undef STAGE_HALF

  // epilogue: C/D layout col=lane&15 (n), row=(lane>>4)*4+reg (m)
  const int colbase = bn0 + wn * 64 + (lane & 15);
  const int rowbase = bm0 + wm * 128 + ((lane >> 4) << 2);
  float bv[4];
#pragma unroll
  for (int nf = 0; nf < 4; ++nf) bv[nf] = bias[colbase + nf * 16];
#pragma unroll
  for (int mf = 0; mf < 8; ++mf)
#pragma unroll
    for (int nf = 0; nf < 4; ++nf) {
      size_t base = (size_t)(rowbase + mf * 16) * NDIM + colbase + nf * 16;
#pragma unroll
      for (int r = 0; r < 4; ++r)
        out[base + (size_t)r * NDIM] = acc[mf][nf][r] + bv[nf];
    }
}

// ---------------- fallback fused 128x128 kernel (ws too small) --------------
__global__ __launch_bounds__(256, 3) void gemm_fused_kernel(
    const float* __restrict__ x, const uint32_t* __restrict__ wq,
    const float* __restrict__ scales, const float* __restrict__ zeros,
    const float* __restrict__ bias, float* __restrict__ out) {
  __shared__ __align__(16) char smem[2 * 128 * 64 * 2];
  char* As = smem;
  char* Bs = smem + 16384;

  const int tid  = threadIdx.x;
  const int lane = tid & 63;
  const int wave = tid >> 6;
  const int wm = wave >> 1, wn = wave & 1;

  const int b   = blockIdx.x;
  const int swz = (b & 7) * 344 + (b >> 3);
  const int mt  = swz / 86;
  const int nt  = swz - mt * 86;
  const int bm0 = mt * 128, bn0 = nt * 128;

  f32x4 acc[4][4];
#pragma unroll
  for (int i = 0; i < 4; ++i)
#pragma unroll
    for (int j = 0; j < 4; ++j) acc[i][j] = (f32x4){0.f, 0.f, 0.f, 0.f};

  const int base_a = ((wm * 64 + (lane & 15)) << 7) + ((lane >> 4) << 4);
  const int base_b = ((wn * 64 + (lane & 15)) << 7) + ((lane >> 4) << 4);

  float sv[4], zv[4];
#pragma unroll
  for (int it = 0; it < 4; ++it) {
    int r = bn0 + it * 32 + (tid >> 3);
    sv[it] = bf16r(scales[r]);
    zv[it] = bf16r(zeros[r]);
  }

  for (int kt = 0; kt < KDIM / 64; ++kt) {
    const int k0 = kt * 64;
    __syncthreads();
#pragma unroll
    for (int it = 0; it < 4; ++it) {
      int ch = it * 256 + tid;
      int row = ch >> 3, c8 = ch & 7;
      const float* src = x + (size_t)(bm0 + row) * KDIM + k0 + c8 * 8;
      float4 f0 = *(const float4*)src;
      float4 f1 = *(const float4*)(src + 4);
      u16x8 v;
      v[0] = f2bf(f0.x); v[1] = f2bf(f0.y); v[2] = f2bf(f0.z); v[3] = f2bf(f0.w);
      v[4] = f2bf(f1.x); v[5] = f2bf(f1.y); v[6] = f2bf(f1.z); v[7] = f2bf(f1.w);
      *(u16x8*)(As + row * 128 + c8 * 16) = v;
    }
#pragma unroll
    for (int it = 0; it < 4; ++it) {
      int ch = it * 256 + tid;
      int row = ch >> 3, kp = ch & 7;
      uint32_t w = wq[(size_t)(bn0 + row) * KP + kt * 8 + kp];
      float s = sv[it], z = zv[it];
      u16x8 v;
#pragma unroll
      for (int j = 0; j < 8; ++j) {
        float qf = (float)((w >> (4 * j)) & 0xF);
        float t  = bf16r(qf * s);
        v[j] = f2bf(t + z);
      }
      *(u16x8*)(Bs + row * 128 + kp * 16) = v;
    }
    __syncthreads();
#pragma unroll
    for (int ks = 0; ks < 2; ++ks) {
      bf16x8 af[4], bf[4];
#pragma unroll
      for (int i = 0; i < 4; ++i)
        af[i] = *(const bf16x8*)(As + base_a + i * 2048 + ks * 64);
#pragma unroll
      for (int j = 0; j < 4; ++j)
        bf[j] = *(const bf16x8*)(Bs + base_b + j * 2048 + ks * 64);
#pragma unroll
      for (int i = 0; i < 4; ++i)
#pragma unroll
        for (int j = 0; j < 4; ++j)
          acc[i][j] = __builtin_amdgcn_mfma_f32_16x16x32_bf16(af[i], bf[j],
                                                              acc[i][j], 0, 0, 0);
    }
  }

  const int colbase = bn0 + wn * 64 + (lane & 15);
  const int rowbase = bm0 + wm * 64 + ((lane >> 4) << 2);
  float bv[4];
#pragma unroll
  for (int j = 0; j < 4; ++j) bv[j] = bias[colbase + j * 16];
#pragma unroll
  for (int i = 0; i < 4; ++i) {
#pragma unroll
    for (int j = 0; j < 4; ++j) {
      size_t base = (size_t)(rowbase + i * 16) * NDIM + colbase + j * 16;
#pragma unroll
      for (int r = 0; r < 4; ++r)
        out[base + (size_t)r * NDIM] = acc[i][j][r] + bv[j];
    }
  }
}

extern "C" void kernel_launch(void* const* d_in, const int* in_sizes, int n_in,
                              void* d_out, int out_size, void* d_ws, size_t ws_size,
                              hipStream_t stream) {
  const float*    x      = (const float*)d_in[0];
  const uint32_t* wq     = (const uint32_t*)d_in[1];
  const float*    scales = (const float*)d_in[2];
  const float*    zeros  = (const float*)d_in[3];
  const float*    bias   = (const float*)d_in[4];
  float*          out    = (float*)d_out;

  const size_t needW = (size_t)NDIM * KDIM * 2;  // 90,177,536 B
  const size_t needX = (size_t)MDIM * KDIM * 2;  // 33,554,432 B

  if (ws_size >= needW + needX) {
    unsigned short* Wbf = (unsigned short*)d_ws;
    unsigned short* Xbf = (unsigned short*)((char*)d_ws + needW);
    dequant_w_kernel<<<(NDIM * KP) / 256, 256, 0, stream>>>(wq, scales, zeros,
                                                            (u16x8*)Wbf);
    convert_x_kernel<<<(MDIM * KDIM / 8) / 256, 256, 0, stream>>>(
        (const float4*)x, (u16x8*)Xbf);
    gemm256_kernel<<<688, 512, 0, stream>>>(Xbf, Wbf, bias, out);
  } else {
    gemm_fused_kernel<<<2752, 256, 0, stream>>>(x, wq, scales, zeros, bias, out);
  }
}